// Round 13
// baseline (340.404 us; speedup 1.0000x reference)
//
#include <hip/hip_runtime.h>
#include <math.h>

typedef _Float16 f16x8 __attribute__((ext_vector_type(8)));
typedef _Float16 f16x4 __attribute__((ext_vector_type(4)));
typedef float f32x4 __attribute__((ext_vector_type(4)));

#define TLEN 512
#define BT 16
#define MFMA(a,b,c) __builtin_amdgcn_mfma_f32_16x16x32_f16(a,b,c,0,0,0)
#define LOG2E 1.44269504f

// Workgroup barrier WITHOUT the vmcnt(0)/expcnt(0) drain __syncthreads emits.
// Safe here: only LDS data crosses the barrier (lgkmcnt(0) orders ds_writes);
// global loads are wave-private (compiler inserts vmcnt waits at use);
// out-stores are never re-read in-kernel.
__device__ __forceinline__ void bar_lds() {
    asm volatile("s_waitcnt lgkmcnt(0)\n\ts_barrier" ::: "memory");
}

// R22 = R21 (292us bench best) minus the ENTIRE Bx LDS apparatus: x lives in
// registers. x is rank-5 and per-lane local (only quad==0 lanes carry k<8 in
// the B-frag; their data is x[n16][t][0..4]) -- it never needed the
// cross-wave LDS path. Each quad0 lane loads its OWN batch row directly
// (10 float4 at sub1, 6-substep latency cover, L2-resident), repacks to f16
// frags at sub7 after last use. Removes/substep: 1 ds_read_b128, sub7
// x-publish, sub1 LDS staging, Bx zero-init, pre-loop sync, 16KB LDS.
// x values bit-identical ((_Float16) RNE as before) -> absmax unchanged.
// Removal ledger: R15b -20cy, R18 -85, R19 -132, R20 -190, R21 -90,
// R22 predicted -10-25cy. If neutral: structural latency floor reached
// (irreducible exchange + minimum 9 MFMA + minimum 24 trans + 1 chain/CU).
__global__ __launch_bounds__(256, 1) void grut1_kernel(
    const float* __restrict__ X, const float* __restrict__ dtp,
    const float* __restrict__ w_ih, const float* __restrict__ w_hh,
    const float* __restrict__ b_ih, const float* __restrict__ b_hh,
    const float* __restrict__ w_dt, const float* __restrict__ b_dt,
    const float* __restrict__ w_out, const float* __restrict__ b_out,
    float* __restrict__ out)
{
    __shared__ __align__(16) _Float16 Bs[2048];    // [phase2][kt2][512] hi only
    __shared__ __align__(16) float PPc[512];       // [wave4][b16][t8]

    const int tid = threadIdx.x;
    const int w = tid >> 6;
    const int l = tid & 63;
    const int n16 = l & 15;
    const int quad = l >> 4;
    const int b0g = blockIdx.x * BT;
    const int hq0 = w * 16 + quad * 4;

    // B-state publish offset (halfwords): k_local = 16(w&1)+4q+r, contiguous r
    const int bsoff = (w >> 1) * 512
                    + (((2 * (w & 1) + (quad >> 1)) * 16) + n16) * 8
                    + (quad & 1) * 4;

    float wdt4[4], bdt4[4], wout4[4];
    f32x4 seedR, seedZ, seedNi, seedNh;
#pragma unroll
    for (int r = 0; r < 4; ++r) {
        int j = hq0 + r;
        wdt4[r] = -LOG2E * w_dt[j];
        bdt4[r] = -LOG2E * b_dt[j];
        wout4[r] = w_out[j];
        seedR[r] = -LOG2E * (b_ih[j] + b_hh[j]);
        seedZ[r] = -LOG2E * (b_ih[64 + j] + b_hh[64 + j]);
        seedNi[r] = 2.f * LOG2E * b_ih[128 + j];
        seedNh[r] = 2.f * LOG2E * b_hh[128 + j];
    }
    const float bout = b_out[0];

    // A-frags (weights), single-plane fp16 RNE, LOG2E-prescaled.
    // gate 0 (R): x(-LOG2E); gate 1 (Z): x(-LOG2E); gate 2 (N): x(+2 LOG2E).
    f16x8 Ah[3][2], Axh[3];
#pragma unroll
    for (int g = 0; g < 3; ++g) {
        const float gs = (g == 2) ? (2.f * LOG2E) : (-LOG2E);
        const int row = g * 64 + w * 16 + n16;
#pragma unroll
        for (int kt = 0; kt < 2; ++kt) {
            const float* src = w_hh + row * 64 + kt * 32 + quad * 8;
            f16x8 hi;
#pragma unroll
            for (int i = 0; i < 8; ++i) hi[i] = (_Float16)(gs * src[i]);
            Ah[g][kt] = hi;
        }
        f16x8 hi;
#pragma unroll
        for (int i = 0; i < 8; ++i) {
            float v = (quad == 0 && i < 5) ? (gs * w_ih[row * 5 + i]) : 0.f;
            hi[i] = (_Float16)v;
        }
        Axh[g] = hi;
    }

    // ---- register-resident x: lane's own batch row ----
    // B-frag for the x k-tile: lane (n16, quad) supplies k = quad*8+j; only
    // k<5 (quad==0, j<5) is x[n16][t][j]; all else zero. xfr[sub] holds the
    // frag for t = tb+sub. quad!=0 lanes keep zero frags forever.
    const float* Xrow5 = X + (size_t)(b0g + n16) * (TLEN * 5);
    f16x8 xfr[8];
#pragma unroll
    for (int s = 0; s < 8; ++s) {
#pragma unroll
        for (int j = 0; j < 8; ++j) xfr[s][j] = (_Float16)0.f;
    }
    float xpre[40];   // prefetch buffer, static-indexed only (stays in VGPRs)
    if (quad == 0) {
#pragma unroll
        for (int i = 0; i < 10; ++i)
            *(float4*)&xpre[i * 4] = *(const float4*)(Xrow5 + i * 4);
#pragma unroll
        for (int s = 0; s < 8; ++s) {
#pragma unroll
            for (int j = 0; j < 5; ++j)
                xfr[s][j] = (_Float16)xpre[s * 5 + j];   // RNE, same as staged
        }
    }

    // chunk-0 dt (lane's batch) + dec for t=0. dec = exp2(min(dt*w'+b', 0)).
    const float* dtb = dtp + (size_t)(b0g + n16) * TLEN;
    float4 dtc0 = *(const float4*)(dtb);
    float4 dtc1 = *(const float4*)(dtb + 4);
    float4 dtn0, dtn1;
    float dcur[4];
#pragma unroll
    for (int r = 0; r < 4; ++r)
        dcur[r] = __builtin_amdgcn_exp2f(fminf(fmaf(dtc0.x, wdt4[r], bdt4[r]), 0.f));

    f32x4 hreg = {0.f, 0.f, 0.f, 0.f};
    float pbuf[8];

#pragma unroll 1
    for (int tb = 0; tb < TLEN; tb += 8) {
#pragma unroll
        for (int sub = 0; sub < 8; ++sub) {
            const int pB = (sub & 1) * 1024;

            // ---- pre-barrier: h_tilde pack (fp16 RNE) + state publish ----
            f32x4 htl;
            f16x4 vh;
#pragma unroll
            for (int r = 0; r < 4; ++r) {
                float v = dcur[r] * hreg[r];
                htl[r] = v;
                vh[r] = (_Float16)v;   // RNE
            }
            *(f16x4*)&Bs[pB + bsoff] = vh;

            bar_lds();   // lgkmcnt(0) + s_barrier only -- NO vmcnt drain

            // ---- post-barrier: B-frag reads (2x ds_read_b128 + reg x) ----
            f16x8 Bh0 = *(const f16x8*)&Bs[pB + l * 8];
            f16x8 Bh1 = *(const f16x8*)&Bs[pB + 512 + l * 8];
            f16x8 Bxh = xfr[sub];

            // prev-chunk output combine, WAVE-BALANCED (32 lanes of each wave;
            // piggybacks on this barrier). base = b*8+t8 with b = w*4+(l>>3).
            if (sub == 0 && tb > 0 && l < 32) {
                int base = w * 32 + l;
                float s = PPc[base] + PPc[128 + base] + PPc[256 + base] + PPc[384 + base];
                out[(size_t)(b0g + (base >> 3)) * TLEN + (tb - 8) + (base & 7)] = s + bout;
            }
            // next-chunk prefetches (latency covered until consumed; no drains)
            if (sub == 1 && tb + 8 < TLEN && quad == 0) {
#pragma unroll
                for (int i = 0; i < 10; ++i)
                    *(float4*)&xpre[i * 4] =
                        *(const float4*)(Xrow5 + (tb + 8) * 5 + i * 4);
            }
            if (sub == 2 && tb + 8 < TLEN) {
                dtn0 = *(const float4*)(dtb + tb + 8);
                dtn1 = *(const float4*)(dtb + tb + 12);
            }

            // ---- 9 MFMA, 4 chains (R:3, Z:3, Nh:2, Ni:1), all pre-scaled ----
            f32x4 aR = seedR, aZ = seedZ, aNi = seedNi, aNh = seedNh;
            aR  = MFMA(Ah[0][0], Bh0, aR);
            aZ  = MFMA(Ah[1][0], Bh0, aZ);
            aNh = MFMA(Ah[2][0], Bh0, aNh);
            aNi = MFMA(Axh[2], Bxh, aNi);
            aR  = MFMA(Ah[0][1], Bh1, aR);
            aZ  = MFMA(Ah[1][1], Bh1, aZ);
            aNh = MFMA(Ah[2][1], Bh1, aNh);
            aR  = MFMA(Axh[0], Bxh, aR);
            aZ  = MFMA(Axh[1], Bxh, aZ);

            // dec for t+1 (under MFMA shadow)
            if (tb + 8 < TLEN || sub < 7) {
                float dnext = (sub == 0) ? dtc0.y : (sub == 1) ? dtc0.z : (sub == 2) ? dtc0.w
                            : (sub == 3) ? dtc1.x : (sub == 4) ? dtc1.y : (sub == 5) ? dtc1.z
                            : (sub == 6) ? dtc1.w : dtn0.x;
#pragma unroll
                for (int r = 0; r < 4; ++r)
                    dcur[r] = __builtin_amdgcn_exp2f(fminf(fmaf(dnext, wdt4[r], bdt4[r]), 0.f));
            }

            // ---- gates (fused single-rcp form) + h update + pred ----
            // rr = 1/(1+exp2(aR)); a = exp2(aZ); E = exp2(aNi + rr*aNh);
            // hv = ((htl+a)*(1+E) - 2a) / ((1+a)*(1+E))
            float p = 0.f;
#pragma unroll
            for (int r = 0; r < 4; ++r) {
                float rr = __builtin_amdgcn_rcpf(1.f + __builtin_amdgcn_exp2f(aR[r]));
                float a  = __builtin_amdgcn_exp2f(aZ[r]);
                float E  = __builtin_amdgcn_exp2f(fmaf(rr, aNh[r], aNi[r]));
                float t2 = 1.f + E;
                float Rv = __builtin_amdgcn_rcpf((1.f + a) * t2);
                float hv = fmaf(htl[r] + a, t2, -(a + a)) * Rv;
                hreg[r] = hv;
                p = fmaf(wout4[r], hv, p);
            }
            pbuf[sub] = p;

            if (sub == 7) {
                // repack next chunk's x frags (xfr[7] already consumed above)
                if (tb + 8 < TLEN && quad == 0) {
#pragma unroll
                    for (int s = 0; s < 8; ++s) {
#pragma unroll
                        for (int j = 0; j < 5; ++j)
                            xfr[s][j] = (_Float16)xpre[s * 5 + j];
                    }
                }
                // deferred pred reductions for the whole chunk (exact same sums)
#pragma unroll
                for (int s = 0; s < 8; ++s) {
                    pbuf[s] += __shfl_xor(pbuf[s], 16, 64);
                    pbuf[s] += __shfl_xor(pbuf[s], 32, 64);
                }
                if (l < 16) {
                    f32x4 v0 = {pbuf[0], pbuf[1], pbuf[2], pbuf[3]};
                    f32x4 v1 = {pbuf[4], pbuf[5], pbuf[6], pbuf[7]};
                    *(f32x4*)&PPc[w * 128 + n16 * 8] = v0;
                    *(f32x4*)&PPc[w * 128 + n16 * 8 + 4] = v1;
                }
                dtc0 = dtn0;
                dtc1 = dtn1;
            }
        }
    }

    // final chunk combine (wave-balanced, same mapping as in-loop)
    __syncthreads();
    if (l < 32) {
        int base = w * 32 + l;
        float s = PPc[base] + PPc[128 + base] + PPc[256 + base] + PPc[384 + base];
        out[(size_t)(b0g + (base >> 3)) * TLEN + (TLEN - 8) + (base & 7)] = s + bout;
    }
}

extern "C" void kernel_launch(void* const* d_in, const int* in_sizes, int n_in,
                              void* d_out, int out_size, void* d_ws, size_t ws_size,
                              hipStream_t stream) {
    const float* X    = (const float*)d_in[0];
    const float* dt   = (const float*)d_in[1];
    const float* w_ih = (const float*)d_in[2];
    const float* w_hh = (const float*)d_in[3];
    const float* b_ih = (const float*)d_in[4];
    const float* b_hh = (const float*)d_in[5];
    const float* w_dt = (const float*)d_in[6];
    const float* b_dt = (const float*)d_in[7];
    const float* w_out = (const float*)d_in[8];
    const float* b_out = (const float*)d_in[9];
    float* out = (float*)d_out;

    grut1_kernel<<<dim3(4096 / BT), dim3(256), 0, stream>>>(
        X, dt, w_ih, w_hh, b_ih, b_hh, w_dt, b_dt, w_out, b_out, out);
}

// Round 14
// 290.562 us; speedup vs baseline: 1.1715x; 1.1715x over previous
//
#include <hip/hip_runtime.h>
#include <math.h>

typedef _Float16 f16x8 __attribute__((ext_vector_type(8)));
typedef _Float16 f16x4 __attribute__((ext_vector_type(4)));
typedef float f32x4 __attribute__((ext_vector_type(4)));

#define TLEN 512
#define BT 16
#define MFMA(a,b,c) __builtin_amdgcn_mfma_f32_16x16x32_f16(a,b,c,0,0,0)
#define LOG2E 1.44269504f

// Workgroup barrier WITHOUT the vmcnt(0)/expcnt(0) drain __syncthreads emits.
// Safe here: only LDS data crosses the barrier (lgkmcnt(0) orders ds_writes);
// global loads are wave-private (compiler inserts vmcnt waits at use);
// out-stores are never re-read in-kernel.
__device__ __forceinline__ void bar_lds() {
    asm volatile("s_waitcnt lgkmcnt(0)\n\ts_barrier" ::: "memory");
}

// R23 = exact revert to R21 (292.8us bench / 231us counter best).
// R22 falsified the last removal hypothesis: register-resident x was a
// CONVERSION (LDS->VGPR apparatus), +32 VGPR pressure, +260cy/substep pure
// stall. R21 is the measured floor of this structure:
//  - 1 ds_write_b64 + barrier + 3 ds_read_b128: irreducible cross-wave
//    exchange for the 64-wide recurrence.
//  - 9 MFMA: exact minimum (3 gates x K=64 h + shared x-tile).
//  - 24 trans: mathematical minimum for sigma,sigma,tanh,decay (fused
//    single-rcp z-combine, LOG2E pre-scaled into weights).
//  - 1 recurrence chain per CU (4096 batches / 16 = 256 = CU count);
//    parallelism cannot apply (R11/R14), reordering cannot apply (R12/R13).
// Removal ledger (351->231us counter): R15b -20cy, R18 -85, R19 -132,
// R20 -190, R21 -90. Every remaining component individually tested.
__global__ __launch_bounds__(256, 1) void grut1_kernel(
    const float* __restrict__ X, const float* __restrict__ dtp,
    const float* __restrict__ w_ih, const float* __restrict__ w_hh,
    const float* __restrict__ b_ih, const float* __restrict__ b_hh,
    const float* __restrict__ w_dt, const float* __restrict__ b_dt,
    const float* __restrict__ w_out, const float* __restrict__ b_out,
    float* __restrict__ out)
{
    __shared__ __align__(16) _Float16 Bs[2048];    // [phase2][kt2][512] hi only
    __shared__ __align__(16) _Float16 Bx[8192];    // [par2][t8][512] hi only
    __shared__ __align__(16) float PPc[512];       // [wave4][b16][t8]

    const int tid = threadIdx.x;
    const int w = tid >> 6;
    const int l = tid & 63;
    const int n16 = l & 15;
    const int quad = l >> 4;
    const int b0g = blockIdx.x * BT;
    const int hq0 = w * 16 + quad * 4;

    // B-state publish offset (halfwords): k_local = 16(w&1)+4q+r, contiguous r
    const int bsoff = (w >> 1) * 512
                    + (((2 * (w & 1) + (quad >> 1)) * 16) + n16) * 8
                    + (quad & 1) * 4;

    float wdt4[4], bdt4[4], wout4[4];
    f32x4 seedR, seedZ, seedNi, seedNh;
#pragma unroll
    for (int r = 0; r < 4; ++r) {
        int j = hq0 + r;
        wdt4[r] = -LOG2E * w_dt[j];
        bdt4[r] = -LOG2E * b_dt[j];
        wout4[r] = w_out[j];
        seedR[r] = -LOG2E * (b_ih[j] + b_hh[j]);
        seedZ[r] = -LOG2E * (b_ih[64 + j] + b_hh[64 + j]);
        seedNi[r] = 2.f * LOG2E * b_ih[128 + j];
        seedNh[r] = 2.f * LOG2E * b_hh[128 + j];
    }
    const float bout = b_out[0];

    // A-frags (weights), single-plane fp16 RNE, LOG2E-prescaled.
    // gate 0 (R): x(-LOG2E); gate 1 (Z): x(-LOG2E); gate 2 (N): x(+2 LOG2E).
    f16x8 Ah[3][2], Axh[3];
#pragma unroll
    for (int g = 0; g < 3; ++g) {
        const float gs = (g == 2) ? (2.f * LOG2E) : (-LOG2E);
        const int row = g * 64 + w * 16 + n16;
#pragma unroll
        for (int kt = 0; kt < 2; ++kt) {
            const float* src = w_hh + row * 64 + kt * 32 + quad * 8;
            f16x8 hi;
#pragma unroll
            for (int i = 0; i < 8; ++i) hi[i] = (_Float16)(gs * src[i]);
            Ah[g][kt] = hi;
        }
        f16x8 hi;
#pragma unroll
        for (int i = 0; i < 8; ++i) {
            float v = (quad == 0 && i < 5) ? (gs * w_ih[row * 5 + i]) : 0.f;
            hi[i] = (_Float16)v;
        }
        Axh[g] = hi;
    }

    // x staging map, WAVE-BALANCED: 640 values/chunk, 160 per wave.
    // v = w*160 + k, k = {l, 64+l, 128+l (l<32)} -> b=v/40, rem=v%40,
    // tt=rem/5, f=rem%5. Within a t-slot (512 hw): addr = b*8 + f.
    int xg[3], xw[3], xvalid[3];
#pragma unroll
    for (int i = 0; i < 3; ++i) {
        int k = l + i * 64;
        xvalid[i] = (i < 2) || (l < 32);
        int v = w * 160 + (xvalid[i] ? k : 0);
        int b = v / 40;
        int rem = v - b * 40;
        int tt = rem / 5;
        int f = rem - tt * 5;
        xg[i] = (b0g + b) * (TLEN * 5) + rem;
        xw[i] = tt * 512 + b * 8 + f;
    }

    // zero Bx (unused K slots must be 0.0f16): 8192 halfwords = 16KB
    {
        float4 z4 = make_float4(0.f, 0.f, 0.f, 0.f);
        float4* p4 = (float4*)Bx;
#pragma unroll
        for (int i = 0; i < 4; ++i) p4[tid + i * 256] = z4;
    }
    __syncthreads();
    // publish chunk-0 x (hi only)
#pragma unroll
    for (int i = 0; i < 3; ++i) if (xvalid[i]) {
        Bx[xw[i]] = (_Float16)X[xg[i]];
    }

    // chunk-0 dt (lane's batch) + dec for t=0. dec = exp2(min(dt*w'+b', 0)).
    const float* dtb = dtp + (size_t)(b0g + n16) * TLEN;
    float4 dtc0 = *(const float4*)(dtb);
    float4 dtc1 = *(const float4*)(dtb + 4);
    float4 dtn0, dtn1;
    float dcur[4];
#pragma unroll
    for (int r = 0; r < 4; ++r)
        dcur[r] = __builtin_amdgcn_exp2f(fminf(fmaf(dtc0.x, wdt4[r], bdt4[r]), 0.f));

    f32x4 hreg = {0.f, 0.f, 0.f, 0.f};
    float pbuf[8];
    float xst[3];

#pragma unroll 1
    for (int tb = 0; tb < TLEN; tb += 8) {
        const int par = (tb >> 3) & 1;
        const int npar = par ^ 1;
#pragma unroll
        for (int sub = 0; sub < 8; ++sub) {
            const int pB = (sub & 1) * 1024;

            // ---- pre-barrier: h_tilde pack (fp16 RNE) + state publish ----
            f32x4 htl;
            f16x4 vh;
#pragma unroll
            for (int r = 0; r < 4; ++r) {
                float v = dcur[r] * hreg[r];
                htl[r] = v;
                vh[r] = (_Float16)v;   // RNE
            }
            *(f16x4*)&Bs[pB + bsoff] = vh;
            if (sub == 7 && tb + 8 < TLEN) {
                // publish next chunk's x-frags (hi only)
#pragma unroll
                for (int i = 0; i < 3; ++i) if (xvalid[i]) {
                    Bx[npar * 4096 + xw[i]] = (_Float16)xst[i];
                }
            }

            bar_lds();   // lgkmcnt(0) + s_barrier only -- NO vmcnt drain

            // ---- post-barrier: B-frag reads (3x ds_read_b128) ----
            f16x8 Bh0 = *(const f16x8*)&Bs[pB + l * 8];
            f16x8 Bh1 = *(const f16x8*)&Bs[pB + 512 + l * 8];
            f16x8 Bxh = *(const f16x8*)&Bx[par * 4096 + sub * 512 + l * 8];

            // prev-chunk output combine, WAVE-BALANCED (32 lanes of each wave;
            // piggybacks on this barrier). base = b*8+t8 with b = w*4+(l>>3).
            if (sub == 0 && tb > 0 && l < 32) {
                int base = w * 32 + l;
                float s = PPc[base] + PPc[128 + base] + PPc[256 + base] + PPc[384 + base];
                out[(size_t)(b0g + (base >> 3)) * TLEN + (tb - 8) + (base & 7)] = s + bout;
            }
            // next-chunk prefetches (latency covered until consumed; no drains)
            if (sub == 1 && tb + 8 < TLEN) {
#pragma unroll
                for (int i = 0; i < 3; ++i) if (xvalid[i]) xst[i] = X[xg[i] + (tb + 8) * 5];
            }
            if (sub == 2 && tb + 8 < TLEN) {
                dtn0 = *(const float4*)(dtb + tb + 8);
                dtn1 = *(const float4*)(dtb + tb + 12);
            }

            // ---- 9 MFMA, 4 chains (R:3, Z:3, Nh:2, Ni:1), all pre-scaled ----
            f32x4 aR = seedR, aZ = seedZ, aNi = seedNi, aNh = seedNh;
            aR  = MFMA(Ah[0][0], Bh0, aR);
            aZ  = MFMA(Ah[1][0], Bh0, aZ);
            aNh = MFMA(Ah[2][0], Bh0, aNh);
            aNi = MFMA(Axh[2], Bxh, aNi);
            aR  = MFMA(Ah[0][1], Bh1, aR);
            aZ  = MFMA(Ah[1][1], Bh1, aZ);
            aNh = MFMA(Ah[2][1], Bh1, aNh);
            aR  = MFMA(Axh[0], Bxh, aR);
            aZ  = MFMA(Axh[1], Bxh, aZ);

            // dec for t+1 (under MFMA shadow)
            if (tb + 8 < TLEN || sub < 7) {
                float dnext = (sub == 0) ? dtc0.y : (sub == 1) ? dtc0.z : (sub == 2) ? dtc0.w
                            : (sub == 3) ? dtc1.x : (sub == 4) ? dtc1.y : (sub == 5) ? dtc1.z
                            : (sub == 6) ? dtc1.w : dtn0.x;
#pragma unroll
                for (int r = 0; r < 4; ++r)
                    dcur[r] = __builtin_amdgcn_exp2f(fminf(fmaf(dnext, wdt4[r], bdt4[r]), 0.f));
            }

            // ---- gates (fused single-rcp form) + h update + pred ----
            // rr = 1/(1+exp2(aR)); a = exp2(aZ); E = exp2(aNi + rr*aNh);
            // hv = ((htl+a)*(1+E) - 2a) / ((1+a)*(1+E))
            float p = 0.f;
#pragma unroll
            for (int r = 0; r < 4; ++r) {
                float rr = __builtin_amdgcn_rcpf(1.f + __builtin_amdgcn_exp2f(aR[r]));
                float a  = __builtin_amdgcn_exp2f(aZ[r]);
                float E  = __builtin_amdgcn_exp2f(fmaf(rr, aNh[r], aNi[r]));
                float t2 = 1.f + E;
                float Rv = __builtin_amdgcn_rcpf((1.f + a) * t2);
                float hv = fmaf(htl[r] + a, t2, -(a + a)) * Rv;
                hreg[r] = hv;
                p = fmaf(wout4[r], hv, p);
            }
            pbuf[sub] = p;

            if (sub == 7) {
                // deferred pred reductions for the whole chunk (exact same sums)
#pragma unroll
                for (int s = 0; s < 8; ++s) {
                    pbuf[s] += __shfl_xor(pbuf[s], 16, 64);
                    pbuf[s] += __shfl_xor(pbuf[s], 32, 64);
                }
                if (l < 16) {
                    f32x4 v0 = {pbuf[0], pbuf[1], pbuf[2], pbuf[3]};
                    f32x4 v1 = {pbuf[4], pbuf[5], pbuf[6], pbuf[7]};
                    *(f32x4*)&PPc[w * 128 + n16 * 8] = v0;
                    *(f32x4*)&PPc[w * 128 + n16 * 8 + 4] = v1;
                }
                dtc0 = dtn0;
                dtc1 = dtn1;
            }
        }
    }

    // final chunk combine (wave-balanced, same mapping as in-loop)
    __syncthreads();
    if (l < 32) {
        int base = w * 32 + l;
        float s = PPc[base] + PPc[128 + base] + PPc[256 + base] + PPc[384 + base];
        out[(size_t)(b0g + (base >> 3)) * TLEN + (TLEN - 8) + (base & 7)] = s + bout;
    }
}

extern "C" void kernel_launch(void* const* d_in, const int* in_sizes, int n_in,
                              void* d_out, int out_size, void* d_ws, size_t ws_size,
                              hipStream_t stream) {
    const float* X    = (const float*)d_in[0];
    const float* dt   = (const float*)d_in[1];
    const float* w_ih = (const float*)d_in[2];
    const float* w_hh = (const float*)d_in[3];
    const float* b_ih = (const float*)d_in[4];
    const float* b_hh = (const float*)d_in[5];
    const float* w_dt = (const float*)d_in[6];
    const float* b_dt = (const float*)d_in[7];
    const float* w_out = (const float*)d_in[8];
    const float* b_out = (const float*)d_in[9];
    float* out = (float*)d_out;

    grut1_kernel<<<dim3(4096 / BT), dim3(256), 0, stream>>>(
        X, dt, w_ih, w_hh, b_ih, b_hh, w_dt, b_dt, w_out, b_out, out);
}